// Round 19
// baseline (285.240 us; speedup 1.0000x reference)
//
#include <hip/hip_runtime.h>
#include <hip/hip_bf16.h>

#define SEQ 2048
#define DM  1024

typedef __attribute__((ext_vector_type(8))) _Float16 f16x8;  // MFMA A/B operand (4 VGPR)
typedef __attribute__((ext_vector_type(4)))  float   f32x4;  // 16x16 C/D

#define EXP2F(x) __builtin_amdgcn_exp2f(x)

__device__ __forceinline__ ushort f2h(float x) {             // fp32 -> fp16 RNE, as bits
    union { _Float16 h; ushort u; } c; c.h = (_Float16)x; return c.u;
}
__device__ __forceinline__ unsigned pk2h(float a, float b) { // 2x fp32 -> packed fp16 (RTZ)
    typedef __fp16 fp16v2 __attribute__((ext_vector_type(2)));
    union { fp16v2 h; unsigned u; } c;
    c.h = __builtin_amdgcn_cvt_pkrtz(a, b);
    return c.u;
}

// ---------- async global->LDS (16B/lane, per-lane global addr, wave-uniform LDS base) ----------
__device__ __forceinline__ void gload16(const void* g, void* l) {
    __builtin_amdgcn_global_load_lds(
        (const __attribute__((address_space(1))) unsigned*)(uintptr_t)g,
        (__attribute__((address_space(3))) unsigned*)(uintptr_t)l, 16, 0, 0);
}

// ============================================================================
// cvt_all: fp32 -> fp16. x (4M) -> xH; wq|wk|wv|wo (4M) -> wH.
// ============================================================================
__global__ __launch_bounds__(256)
void cvt_all(const float* __restrict__ x,  const float* __restrict__ wq,
             const float* __restrict__ wk, const float* __restrict__ wv,
             const float* __restrict__ wo,
             ushort* __restrict__ xH, ushort* __restrict__ wH)
{
    const int NX4 = (2 * SEQ * DM) / 4;     // 1,048,576 float4
    const int NW4 = (DM * DM) / 4;          //   262,144 float4 per weight
    const int total = NX4 + 4 * NW4;
    for (int i = blockIdx.x * 256 + threadIdx.x; i < total; i += gridDim.x * 256) {
        float4 v; ushort4* dst;
        if (i < NX4) {
            v = ((const float4*)x)[i];
            dst = (ushort4*)xH + i;
        } else {
            const int j = i - NX4;
            const int wi = j >> 18;
            const int jo = j & (NW4 - 1);
            const float* ws_ = (wi == 0) ? wq : (wi == 1) ? wk : (wi == 2) ? wv : wo;
            v = ((const float4*)ws_)[jo];
            dst = (ushort4*)wH + j;
        }
        ushort4 h;
        h.x = f2h(v.x); h.y = f2h(v.y); h.z = f2h(v.z); h.w = f2h(v.w);
        *dst = h;
    }
}

// ============================================================================
// GEMM v5: fp16 single-term, counted-vmcnt pipelined (T3+T4+T5).
// (unchanged from R9-R18)
// ============================================================================
template<int BM, int BN, int WM, int WN, int MODE>
__global__ __launch_bounds__(WM * WN * 64)
void gemm5(const ushort* __restrict__ A, const ushort* __restrict__ B,
           const float* __restrict__ b0, const float* __restrict__ b1,
           const float* __restrict__ b2,
           ushort* __restrict__ QH, ushort* __restrict__ KH,
           ushort* __restrict__ VH, float* __restrict__ outf, int nmt)
{
    constexpr int NW  = WM * WN;
    constexpr int PR  = BM / WM, PC = BN / WN;
    constexpr int MR  = PR / 16, NR = PC / 16, MH = MR / 2;
    constexpr int APW = (BM / 8) / NW;
    constexpr int BPW = (BN / 8) / NW;
    constexpr int NT  = DM / 64;

    __shared__ ushort A_lds[2][BM * 64];
    __shared__ ushort B_lds[2][BN * 64];

    const int tid = threadIdx.x, w = tid >> 6, lane = tid & 63;
    const int nwg = gridDim.x, q8 = nwg >> 3;
    const int wg  = (blockIdx.x & 7) * q8 + (blockIdx.x >> 3);
    const int m0  = (wg % nmt) * BM, n0 = (wg / nmt) * BN;
    const int wm  = w / WN, wn = w % WN;

    auto stage = [&](int buf, int kt) {
        const int k0 = kt * 64;
#pragma unroll
        for (int j = 0; j < APW; ++j) {
            const int s   = w * APW + j;
            const int row = s * 8 + (lane >> 3);
            const int cl  = (lane & 7) ^ (row & 7);
            gload16(A + (size_t)(m0 + row) * DM + k0 + cl * 8,
                    &A_lds[buf][s * 512]);
        }
#pragma unroll
        for (int j = 0; j < BPW; ++j) {
            const int s   = w * BPW + j;
            const int row = s * 8 + (lane >> 3);
            const int cl  = (lane & 7) ^ (row & 7);
            gload16(B + (size_t)(n0 + row) * DM + k0 + cl * 8,
                    &B_lds[buf][s * 512]);
        }
    };

    f32x4 acc[MR][NR];
#pragma unroll
    for (int i = 0; i < MR; ++i)
#pragma unroll
        for (int j = 0; j < NR; ++j) acc[i][j] = f32x4{0.f, 0.f, 0.f, 0.f};

    stage(0, 0);
    stage(1, 1);

    for (int t = 0; t < NT; ++t) {
        const int buf = t & 1;
        if (t == NT - 1) asm volatile("s_waitcnt vmcnt(0)" ::: "memory");
        else             asm volatile("s_waitcnt vmcnt(8)" ::: "memory");
        __builtin_amdgcn_sched_barrier(0);
        __builtin_amdgcn_s_barrier();

        f16x8 bf_[NR][2];
#pragma unroll
        for (int nf = 0; nf < NR; ++nf) {
            const int r = wn * PC + nf * 16 + (lane & 15);
#pragma unroll
            for (int kb = 0; kb < 2; ++kb) {
                const int c = kb * 4 + (lane >> 4);
                bf_[nf][kb] = *(const f16x8*)&B_lds[buf][r * 64 + ((c ^ (r & 7)) << 3)];
            }
        }
#pragma unroll
        for (int qm = 0; qm < 2; ++qm) {
            f16x8 af_[MH][2];
#pragma unroll
            for (int mf = 0; mf < MH; ++mf) {
                const int r = wm * PR + qm * (PR / 2) + mf * 16 + (lane & 15);
#pragma unroll
                for (int kb = 0; kb < 2; ++kb) {
                    const int c = kb * 4 + (lane >> 4);
                    af_[mf][kb] = *(const f16x8*)&A_lds[buf][r * 64 + ((c ^ (r & 7)) << 3)];
                }
            }
            __builtin_amdgcn_s_setprio(1);
#pragma unroll
            for (int kb = 0; kb < 2; ++kb)
#pragma unroll
                for (int mf = 0; mf < MH; ++mf)
#pragma unroll
                    for (int nf = 0; nf < NR; ++nf)
                        acc[qm * MH + mf][nf] = __builtin_amdgcn_mfma_f32_16x16x32_f16(
                            af_[mf][kb], bf_[nf][kb], acc[qm * MH + mf][nf], 0, 0, 0);
            __builtin_amdgcn_s_setprio(0);
        }
        __builtin_amdgcn_sched_barrier(0);
        __builtin_amdgcn_s_barrier();
        __builtin_amdgcn_sched_barrier(0);
        if (t + 2 < NT) stage(buf, t + 2);
    }

#pragma unroll
    for (int mf = 0; mf < MR; ++mf)
#pragma unroll
        for (int nf = 0; nf < NR; ++nf) {
            const int col  = n0 + wn * PC + nf * 16 + (lane & 15);
            const int row0 = m0 + wm * PR + mf * 16 + ((lane >> 4) << 2);
            f32x4 v = acc[mf][nf];
            if constexpr (MODE == 1) {
                float4 o;
                o.x = v[0] + b0[row0 + 0];
                o.y = v[1] + b0[row0 + 1];
                o.z = v[2] + b0[row0 + 2];
                o.w = v[3] + b0[row0 + 3];
                *(float4*)&outf[(size_t)col * DM + row0] = o;
            } else {
                const int sel = row0 >> 10;          // 0=Q 1=K 2=V
                const int e = row0 & 1023;
                const int b = col >> 11, s = col & 2047;
                const int h = e >> 6, dk = e & 63;
                const float* bp = (sel == 0) ? b0 : (sel == 1) ? b1 : b2;
                const float sc = (sel == 0) ? 0.125f * 1.44269504089f : 1.0f;
                const float v0 = (v[0] + bp[e + 0]) * sc;
                const float v1 = (v[1] + bp[e + 1]) * sc;
                const float v2 = (v[2] + bp[e + 2]) * sc;
                const float v3 = (v[3] + bp[e + 3]) * sc;
                const int bh = b * 16 + h;
                ushort4 hv;
                hv.x = f2h(v0); hv.y = f2h(v1); hv.z = f2h(v2); hv.w = f2h(v3);
                if (sel == 0) {
                    const size_t off = ((size_t)bh * SEQ + s) * 64 + dk;
                    *(ushort4*)&QH[off] = hv;
                } else if (sel == 1) {
                    const size_t off = ((size_t)bh * SEQ + s) * 64 + dk;
                    *(ushort4*)&KH[off] = hv;
                } else {   // V transposed: [bh][dk][s]
                    const size_t o0 = ((size_t)bh * 64 + dk) * SEQ + s;
                    VH[o0]           = hv.x;
                    VH[o0 + SEQ]     = hv.y;
                    VH[o0 + 2 * SEQ] = hv.z;
                    VH[o0 + 3 * SEQ] = hv.w;
                }
            }
        }
}

// ============================================================================
// Flash attention v15: ZERO-STAGING / ZERO-BARRIER.
// K and V^T fragments are read DIRECTLY from global (L1/L2-resident: per-bh
// K+V = 512 KB; XCD swizzle keeps the 32 q-tile blocks of 4 bh on one XCD's
// private L2; a tile's 16 KB working set is L1-resident for the block's
// 4 waves).  Only per-wave Ps (P round-trip for the PV operand swap) stays
// in LDS (8 KB/block) -> no __syncthreads anywhere; waves free-run so
// QK(MFMA) / exp2(VALU) / PV(MFMA) of different waves overlap.
// No-max softmax (exp2-space, safe), split-PV, lane-local l.
// 4-wave blocks, q-tile 64, grid 1024 (4 blocks/CU, 16 waves/CU).
// ============================================================================
__global__ __launch_bounds__(256, 4)
void attn_k(const ushort* __restrict__ QH, const ushort* __restrict__ KH,
            const ushort* __restrict__ VH, const int* __restrict__ mask,
            ushort* __restrict__ ch)
{
    __shared__ ushort Ps[4][16 * 64];   // per-wave P^T [q 16][8 chunks] over keys

    const int t = threadIdx.x, w = t >> 6, lane = t & 63;
    const int wg = (blockIdx.x & 7) * 128 + (blockIdx.x >> 3);  // XCD swizzle (1024 wgs)
    const int bh = wg >> 5, qt = wg & 31;
    const int b = bh >> 4, h = bh & 15;
    const int q0 = qt * 64 + w * 16;
    const size_t base = (size_t)bh * SEQ * 64;
    const int lq = lane & 15, cb = lane >> 4;

    // Q fragments; masked q-rows get Q=0 -> scores=0 -> P=1 (== reference)
    const int msk = mask[b * SEQ + q0 + lq];
    f16x8 qf[2];
#pragma unroll
    for (int kb = 0; kb < 2; ++kb) {
        qf[kb] = *(const f16x8*)&QH[base + (size_t)(q0 + lq) * 64 + kb * 32 + cb * 8];
        if (msk == 0) qf[kb] = f16x8{0, 0, 0, 0, 0, 0, 0, 0};
    }

    float l_part = 0.f;                 // lane-local; reduced in epilogue
    f32x4 acc[4];
#pragma unroll
    for (int df = 0; df < 4; ++df) acc[df] = f32x4{0.f, 0.f, 0.f, 0.f};

    // global fragment base pointers (16B-contiguous per lane)
    //  K row  = key (A-frag: row = lane&15, k-run = dk)
    //  V^T row = d  (A-frag: row = lane&15, k-run = keys)
    const ushort* Kp = KH + base + (size_t)lq * 64 + cb * 8;       // + key*64 (+16*64 per mf) + kb*32
    const ushort* Vp = VH + base + (size_t)lq * SEQ + cb * 8;      // + d*SEQ (+16*SEQ per df) + kt*64 + kb*32

#pragma unroll 1
    for (int kt = 0; kt < SEQ / 64; ++kt) {
        const int k64 = kt * 64;

        // ---- QK fragments straight from global (L1/L2) ----
        f16x8 kf[4][2];
#pragma unroll
        for (int mf = 0; mf < 4; ++mf)
#pragma unroll
            for (int kb = 0; kb < 2; ++kb)
                kf[mf][kb] = *(const f16x8*)&Kp[(size_t)(k64 + mf * 16) * 64 + kb * 32];

        // ---- V fragments for this tile (issued early; consumed after exp2) ----
        f16x8 vf[4][2];
#pragma unroll
        for (int df = 0; df < 4; ++df)
#pragma unroll
            for (int kb = 0; kb < 2; ++kb)
                vf[df][kb] = *(const f16x8*)&Vp[(size_t)df * 16 * SEQ + k64 + kb * 32];

        // ---- S^T = K * Q^T (exp2-space scores) ----
        f32x4 st[4];
#pragma unroll
        for (int mf = 0; mf < 4; ++mf) st[mf] = f32x4{0.f, 0.f, 0.f, 0.f};
        __builtin_amdgcn_s_setprio(1);
#pragma unroll
        for (int mf = 0; mf < 4; ++mf)
#pragma unroll
            for (int kb = 0; kb < 2; ++kb)
                st[mf] = __builtin_amdgcn_mfma_f32_16x16x32_f16(kf[mf][kb], qf[kb], st[mf], 0, 0, 0);
        __builtin_amdgcn_s_setprio(0);

        // ---- split softmax/PV (no max subtraction; safe: s <= ~12) ----
#pragma unroll
        for (int mf = 0; mf < 2; ++mf) {           // keys 0-31 -> logical chunks 0-3
            const float e0 = EXP2F(st[mf][0]);
            const float e1 = EXP2F(st[mf][1]);
            const float e2 = EXP2F(st[mf][2]);
            const float e3 = EXP2F(st[mf][3]);
            l_part += (e0 + e1) + (e2 + e3);
            uint2 pw;
            pw.x = pk2h(e0, e1);
            pw.y = pk2h(e2, e3);
            const int key0 = mf * 16 + (cb << 2);
            const int p = (key0 >> 3) ^ (lq & 7);
            *(uint2*)&Ps[w][lq * 64 + p * 8 + (key0 & 7)] = pw;
        }
        {   // PV kb=0
            const int p0 = cb ^ (lq & 7);
            f16x8 pf0 = *(const f16x8*)&Ps[w][lq * 64 + p0 * 8];
            __builtin_amdgcn_s_setprio(1);
#pragma unroll
            for (int df = 0; df < 4; ++df)
                acc[df] = __builtin_amdgcn_mfma_f32_16x16x32_f16(vf[df][0], pf0, acc[df], 0, 0, 0);
            __builtin_amdgcn_s_setprio(0);
        }
#pragma unroll
        for (int mf = 2; mf < 4; ++mf) {           // keys 32-63 -> logical chunks 4-7
            const float e0 = EXP2F(st[mf][0]);
            const float e1 = EXP2F(st[mf][1]);
            const float e2 = EXP2F(st[mf][2]);
            const float e3 = EXP2F(st[mf][3]);
            l_part += (e0 + e1) + (e2 + e3);
            uint2 pw;
            pw.x = pk2h(e0, e1);
            pw.y = pk2h(e2, e3);
            const int key0 = mf * 16 + (cb << 2);
            const int p = (key0 >> 3) ^ (lq & 7);
            *(uint2*)&Ps[w][lq * 64 + p * 8 + (key0 & 7)] = pw;
        }
        {   // PV kb=1
            const int p1 = (4 + cb) ^ (lq & 7);
            f16x8 pf1 = *(const f16x8*)&Ps[w][lq * 64 + p1 * 8];
            __builtin_amdgcn_s_setprio(1);
#pragma unroll
            for (int df = 0; df < 4; ++df)
                acc[df] = __builtin_amdgcn_mfma_f32_16x16x32_f16(vf[df][1], pf1, acc[df], 0, 0, 0);
            __builtin_amdgcn_s_setprio(0);
        }
    }

    // ---- epilogue: reduce l across the 4 cb groups; write ctx fp16 ----
    {
        float l_tot = l_part;
        l_tot += __shfl_xor(l_tot, 16);
        l_tot += __shfl_xor(l_tot, 32);
        const float inv = 1.0f / l_tot;
        const int s = q0 + lq;
#pragma unroll
        for (int df = 0; df < 4; ++df) {
            const int e0 = h * 64 + df * 16 + (cb << 2);
            ushort4 hv;
            hv.x = f2h(acc[df][0] * inv);
            hv.y = f2h(acc[df][1] * inv);
            hv.z = f2h(acc[df][2] * inv);
            hv.w = f2h(acc[df][3] * inv);
            *(ushort4*)&ch[(size_t)(b * SEQ + s) * DM + e0] = hv;
        }
    }
}

extern "C" void kernel_launch(void* const* d_in, const int* in_sizes, int n_in,
                              void* d_out, int out_size, void* d_ws, size_t ws_size,
                              hipStream_t stream)
{
    const float* x  = (const float*)d_in[0];
    const int* mask = (const int*)d_in[1];
    const float* wq = (const float*)d_in[2];
    const float* bq = (const float*)d_in[3];
    const float* wk = (const float*)d_in[4];
    const float* bk = (const float*)d_in[5];
    const float* wv = (const float*)d_in[6];
    const float* bv = (const float*)d_in[7];
    const float* wo = (const float*)d_in[8];
    const float* bo = (const float*)d_in[9];
    float* out = (float*)d_out;

    const size_t M1 = 1024 * 1024;      // 1M elements
    ushort* W = (ushort*)d_ws;          // fp16 arena (40 MB used)
    ushort* xH = W;                     // 4M  (doubles as ctx after attn)
    ushort* wH = W + 4 * M1;            // 4M: wq|wk|wv|wo
    ushort* QH = W + 8 * M1;
    ushort* KH = W + 12 * M1;
    ushort* VH = W + 16 * M1;

    cvt_all<<<2048, 256, 0, stream>>>(x, wq, wk, wv, wo, xH, wH);

    gemm5<384, 128, 4, 2, 0><<<256, 512, 0, stream>>>(
        wH, xH, bq, bk, bv, QH, KH, VH, nullptr, 8);

    // attention: 1024 blocks (32 bh x 32 q-tiles, XCD-swizzled), 4 waves each
    attn_k<<<1024, 256, 0, stream>>>(QH, KH, VH, mask, xH);

    gemm5<128, 128, 2, 2, 1><<<256, 256, 0, stream>>>(
        wH + 3 * M1, xH, bo, nullptr, nullptr,
        nullptr, nullptr, nullptr, out, 8);
}

// Round 20
// 103.442 us; speedup vs baseline: 2.7575x; 2.7575x over previous
//
#include <hip/hip_runtime.h>
#include <hip/hip_bf16.h>

#define SEQ 2048
#define DM  1024

typedef __attribute__((ext_vector_type(8))) _Float16 f16x8;  // MFMA A/B operand (4 VGPR)
typedef __attribute__((ext_vector_type(4)))  float   f32x4;  // 16x16 C/D

#define EXP2F(x) __builtin_amdgcn_exp2f(x)

__device__ __forceinline__ ushort f2h(float x) {             // fp32 -> fp16 RNE, as bits
    union { _Float16 h; ushort u; } c; c.h = (_Float16)x; return c.u;
}
__device__ __forceinline__ unsigned pk2h(float a, float b) { // 2x fp32 -> packed fp16 (RTZ)
    typedef __fp16 fp16v2 __attribute__((ext_vector_type(2)));
    union { fp16v2 h; unsigned u; } c;
    c.h = __builtin_amdgcn_cvt_pkrtz(a, b);
    return c.u;
}

// ---------- async global->LDS (16B/lane, per-lane global addr, wave-uniform LDS base) ----------
__device__ __forceinline__ void gload16(const void* g, void* l) {
    __builtin_amdgcn_global_load_lds(
        (const __attribute__((address_space(1))) unsigned*)(uintptr_t)g,
        (__attribute__((address_space(3))) unsigned*)(uintptr_t)l, 16, 0, 0);
}

// ============================================================================
// cvt_all: fp32 -> fp16. x (4M) -> xH; wq|wk|wv|wo (4M) -> wH.
// ============================================================================
__global__ __launch_bounds__(256)
void cvt_all(const float* __restrict__ x,  const float* __restrict__ wq,
             const float* __restrict__ wk, const float* __restrict__ wv,
             const float* __restrict__ wo,
             ushort* __restrict__ xH, ushort* __restrict__ wH)
{
    const int NX4 = (2 * SEQ * DM) / 4;     // 1,048,576 float4
    const int NW4 = (DM * DM) / 4;          //   262,144 float4 per weight
    const int total = NX4 + 4 * NW4;
    for (int i = blockIdx.x * 256 + threadIdx.x; i < total; i += gridDim.x * 256) {
        float4 v; ushort4* dst;
        if (i < NX4) {
            v = ((const float4*)x)[i];
            dst = (ushort4*)xH + i;
        } else {
            const int j = i - NX4;
            const int wi = j >> 18;
            const int jo = j & (NW4 - 1);
            const float* ws_ = (wi == 0) ? wq : (wi == 1) ? wk : (wi == 2) ? wv : wo;
            v = ((const float4*)ws_)[jo];
            dst = (ushort4*)wH + j;
        }
        ushort4 h;
        h.x = f2h(v.x); h.y = f2h(v.y); h.z = f2h(v.z); h.w = f2h(v.w);
        *dst = h;
    }
}

// ============================================================================
// GEMM v5: fp16 single-term, counted-vmcnt pipelined (T3+T4+T5).
// (unchanged from R9-R18)
// ============================================================================
template<int BM, int BN, int WM, int WN, int MODE>
__global__ __launch_bounds__(WM * WN * 64)
void gemm5(const ushort* __restrict__ A, const ushort* __restrict__ B,
           const float* __restrict__ b0, const float* __restrict__ b1,
           const float* __restrict__ b2,
           ushort* __restrict__ QH, ushort* __restrict__ KH,
           ushort* __restrict__ VH, float* __restrict__ outf, int nmt)
{
    constexpr int NW  = WM * WN;
    constexpr int PR  = BM / WM, PC = BN / WN;
    constexpr int MR  = PR / 16, NR = PC / 16, MH = MR / 2;
    constexpr int APW = (BM / 8) / NW;
    constexpr int BPW = (BN / 8) / NW;
    constexpr int NT  = DM / 64;

    __shared__ ushort A_lds[2][BM * 64];
    __shared__ ushort B_lds[2][BN * 64];

    const int tid = threadIdx.x, w = tid >> 6, lane = tid & 63;
    const int nwg = gridDim.x, q8 = nwg >> 3;
    const int wg  = (blockIdx.x & 7) * q8 + (blockIdx.x >> 3);
    const int m0  = (wg % nmt) * BM, n0 = (wg / nmt) * BN;
    const int wm  = w / WN, wn = w % WN;

    auto stage = [&](int buf, int kt) {
        const int k0 = kt * 64;
#pragma unroll
        for (int j = 0; j < APW; ++j) {
            const int s   = w * APW + j;
            const int row = s * 8 + (lane >> 3);
            const int cl  = (lane & 7) ^ (row & 7);
            gload16(A + (size_t)(m0 + row) * DM + k0 + cl * 8,
                    &A_lds[buf][s * 512]);
        }
#pragma unroll
        for (int j = 0; j < BPW; ++j) {
            const int s   = w * BPW + j;
            const int row = s * 8 + (lane >> 3);
            const int cl  = (lane & 7) ^ (row & 7);
            gload16(B + (size_t)(n0 + row) * DM + k0 + cl * 8,
                    &B_lds[buf][s * 512]);
        }
    };

    f32x4 acc[MR][NR];
#pragma unroll
    for (int i = 0; i < MR; ++i)
#pragma unroll
        for (int j = 0; j < NR; ++j) acc[i][j] = f32x4{0.f, 0.f, 0.f, 0.f};

    stage(0, 0);
    stage(1, 1);

    for (int t = 0; t < NT; ++t) {
        const int buf = t & 1;
        if (t == NT - 1) asm volatile("s_waitcnt vmcnt(0)" ::: "memory");
        else             asm volatile("s_waitcnt vmcnt(8)" ::: "memory");
        __builtin_amdgcn_sched_barrier(0);
        __builtin_amdgcn_s_barrier();

        f16x8 bf_[NR][2];
#pragma unroll
        for (int nf = 0; nf < NR; ++nf) {
            const int r = wn * PC + nf * 16 + (lane & 15);
#pragma unroll
            for (int kb = 0; kb < 2; ++kb) {
                const int c = kb * 4 + (lane >> 4);
                bf_[nf][kb] = *(const f16x8*)&B_lds[buf][r * 64 + ((c ^ (r & 7)) << 3)];
            }
        }
#pragma unroll
        for (int qm = 0; qm < 2; ++qm) {
            f16x8 af_[MH][2];
#pragma unroll
            for (int mf = 0; mf < MH; ++mf) {
                const int r = wm * PR + qm * (PR / 2) + mf * 16 + (lane & 15);
#pragma unroll
                for (int kb = 0; kb < 2; ++kb) {
                    const int c = kb * 4 + (lane >> 4);
                    af_[mf][kb] = *(const f16x8*)&A_lds[buf][r * 64 + ((c ^ (r & 7)) << 3)];
                }
            }
            __builtin_amdgcn_s_setprio(1);
#pragma unroll
            for (int kb = 0; kb < 2; ++kb)
#pragma unroll
                for (int mf = 0; mf < MH; ++mf)
#pragma unroll
                    for (int nf = 0; nf < NR; ++nf)
                        acc[qm * MH + mf][nf] = __builtin_amdgcn_mfma_f32_16x16x32_f16(
                            af_[mf][kb], bf_[nf][kb], acc[qm * MH + mf][nf], 0, 0, 0);
            __builtin_amdgcn_s_setprio(0);
        }
        __builtin_amdgcn_sched_barrier(0);
        __builtin_amdgcn_s_barrier();
        __builtin_amdgcn_sched_barrier(0);
        if (t + 2 < NT) stage(buf, t + 2);
    }

#pragma unroll
    for (int mf = 0; mf < MR; ++mf)
#pragma unroll
        for (int nf = 0; nf < NR; ++nf) {
            const int col  = n0 + wn * PC + nf * 16 + (lane & 15);
            const int row0 = m0 + wm * PR + mf * 16 + ((lane >> 4) << 2);
            f32x4 v = acc[mf][nf];
            if constexpr (MODE == 1) {
                float4 o;
                o.x = v[0] + b0[row0 + 0];
                o.y = v[1] + b0[row0 + 1];
                o.z = v[2] + b0[row0 + 2];
                o.w = v[3] + b0[row0 + 3];
                *(float4*)&outf[(size_t)col * DM + row0] = o;
            } else {
                const int sel = row0 >> 10;          // 0=Q 1=K 2=V
                const int e = row0 & 1023;
                const int b = col >> 11, s = col & 2047;
                const int h = e >> 6, dk = e & 63;
                const float* bp = (sel == 0) ? b0 : (sel == 1) ? b1 : b2;
                const float sc = (sel == 0) ? 0.125f * 1.44269504089f : 1.0f;
                const float v0 = (v[0] + bp[e + 0]) * sc;
                const float v1 = (v[1] + bp[e + 1]) * sc;
                const float v2 = (v[2] + bp[e + 2]) * sc;
                const float v3 = (v[3] + bp[e + 3]) * sc;
                const int bh = b * 16 + h;
                ushort4 hv;
                hv.x = f2h(v0); hv.y = f2h(v1); hv.z = f2h(v2); hv.w = f2h(v3);
                if (sel == 0) {
                    const size_t off = ((size_t)bh * SEQ + s) * 64 + dk;
                    *(ushort4*)&QH[off] = hv;
                } else if (sel == 1) {
                    const size_t off = ((size_t)bh * SEQ + s) * 64 + dk;
                    *(ushort4*)&KH[off] = hv;
                } else {   // V transposed: [bh][dk][s]
                    const size_t o0 = ((size_t)bh * 64 + dk) * SEQ + s;
                    VH[o0]           = hv.x;
                    VH[o0 + SEQ]     = hv.y;
                    VH[o0 + 2 * SEQ] = hv.z;
                    VH[o0 + 3 * SEQ] = hv.w;
                }
            }
        }
}

// ============================================================================
// Flash attention v16: R18 schedule (quad-buffer, 2 tiles/barrier-pair,
// no-max softmax, split-PV, lane-local l) with K/V staging moved to
// global_load_lds DMA (no VGPR roundtrip, no wave ds_writes):
//   per pair: vmcnt(4) [pair j landed, j+1 in flight] -> raw barrier ->
//   compute 2 tiles -> lgkmcnt(0) + raw barrier [reads done] ->
//   DMA-issue pair j+2 into freed buffers.
// LDS 80 KB: Ks 4x8K + Vs 4x8K + Ps 8x2K -> 2 blocks/CU.
// q-tile 128, 8 waves x 16 q, grid 512 XCD-swizzled.
// ============================================================================
__global__ __launch_bounds__(512, 2)
void attn_k(const ushort* __restrict__ QH, const ushort* __restrict__ KH,
            const ushort* __restrict__ VH, const int* __restrict__ mask,
            ushort* __restrict__ ch)
{
    __shared__ ushort Ks[4][64 * 64];   // [key][8 chunks of 8] over dk
    __shared__ ushort Vs[4][64 * 64];   // [d][8 chunks] over keys
    __shared__ ushort Ps[8][16 * 64];   // per-wave P^T [q 16][8 chunks] over keys

    const int t = threadIdx.x, w = t >> 6, lane = t & 63;
    const int wg = (blockIdx.x & 7) * 64 + (blockIdx.x >> 3);   // XCD swizzle
    const int bh = wg >> 4, qt = wg & 15;
    const int b = bh >> 4, h = bh & 15;
    const int q0 = qt * 128 + w * 16;
    const size_t base = (size_t)bh * SEQ * 64;
    const int lq = lane & 15, cb = lane >> 4;

    // Q fragments; masked q-rows get Q=0 -> scores=0 -> P=1 (== reference)
    const int msk = mask[b * SEQ + q0 + lq];
    f16x8 qf[2];
#pragma unroll
    for (int kb = 0; kb < 2; ++kb) {
        qf[kb] = *(const f16x8*)&QH[base + (size_t)(q0 + lq) * 64 + kb * 32 + cb * 8];
        if (msk == 0) qf[kb] = f16x8{0, 0, 0, 0, 0, 0, 0, 0};
    }

    float l_part = 0.f;                 // lane-local; reduced in epilogue
    f32x4 acc[4];
#pragma unroll
    for (int df = 0; df < 4; ++df) acc[df] = f32x4{0.f, 0.f, 0.f, 0.f};

    // DMA staging: 512 threads cover 64 rows x 8 chunk-slots; each thread
    // issues 1 gload16 per K-tile and per V-tile.  LDS dest = wave-uniform
    // &Ks[buf][w*512] (+ lane*16B by HW) -> row = w*8+(lane>>3), slot = lane&7.
    // Source carries the inverse chunk swizzle (rule #21).
    const int srow = w * 8 + (lane >> 3);
    const int scl  = (lane & 7) ^ (srow & 7);          // logical chunk for this slot
    const ushort* gK = &KH[base + (size_t)srow * 64 + scl * 8];   // += 4096/tile
    const ushort* gV = &VH[base + (size_t)srow * SEQ + scl * 8];  // += 64/tile
    const int wbase = w * 512;
    auto issue_pair = [&](const int B0, const int B1) {
        gload16(gK, &Ks[B0][wbase]); gK += 4096;
        gload16(gV, &Vs[B0][wbase]); gV += 64;
        gload16(gK, &Ks[B1][wbase]); gK += 4096;
        gload16(gV, &Vs[B1][wbase]); gV += 64;
    };

    // prologue: pair0 -> bufs {0,1}, pair1 -> bufs {2,3}  (8 loads in flight)
    issue_pair(0, 1);
    issue_pair(2, 3);

    // compute one key-tile from Ks[BUF]/Vs[BUF] (BUF literal -> folded)
    auto compute = [&](const int BUF) {
        // ---- S^T = K * Q^T (exp2-space scores) ----
        f32x4 st[4];
#pragma unroll
        for (int mf = 0; mf < 4; ++mf) st[mf] = f32x4{0.f, 0.f, 0.f, 0.f};
        __builtin_amdgcn_s_setprio(1);
#pragma unroll
        for (int mf = 0; mf < 4; ++mf) {
            const int r = mf * 16 + lq;
#pragma unroll
            for (int kb = 0; kb < 2; ++kb) {
                const int p = (kb * 4 + cb) ^ (r & 7);
                f16x8 kf = *(const f16x8*)&Ks[BUF][r * 64 + p * 8];
                st[mf] = __builtin_amdgcn_mfma_f32_16x16x32_f16(kf, qf[kb], st[mf], 0, 0, 0);
            }
        }
        __builtin_amdgcn_s_setprio(0);

        // ---- split softmax/PV (no max subtraction; safe: s <= ~12) ----
#pragma unroll
        for (int mf = 0; mf < 2; ++mf) {           // keys 0-31 -> logical chunks 0-3
            const float e0 = EXP2F(st[mf][0]);
            const float e1 = EXP2F(st[mf][1]);
            const float e2 = EXP2F(st[mf][2]);
            const float e3 = EXP2F(st[mf][3]);
            l_part += (e0 + e1) + (e2 + e3);
            uint2 pw;
            pw.x = pk2h(e0, e1);
            pw.y = pk2h(e2, e3);
            const int key0 = mf * 16 + (cb << 2);
            const int p = (key0 >> 3) ^ (lq & 7);
            *(uint2*)&Ps[w][lq * 64 + p * 8 + (key0 & 7)] = pw;
        }
        {   // PV kb=0
            const int p0 = cb ^ (lq & 7);
            f16x8 pf0 = *(const f16x8*)&Ps[w][lq * 64 + p0 * 8];
            __builtin_amdgcn_s_setprio(1);
#pragma unroll
            for (int df = 0; df < 4; ++df) {
                const int r = df * 16 + lq;
                const int p = cb ^ (r & 7);
                f16x8 vf = *(const f16x8*)&Vs[BUF][r * 64 + p * 8];
                acc[df] = __builtin_amdgcn_mfma_f32_16x16x32_f16(vf, pf0, acc[df], 0, 0, 0);
            }
            __builtin_amdgcn_s_setprio(0);
        }
#pragma unroll
        for (int mf = 2; mf < 4; ++mf) {           // keys 32-63 -> logical chunks 4-7
            const float e0 = EXP2F(st[mf][0]);
            const float e1 = EXP2F(st[mf][1]);
            const float e2 = EXP2F(st[mf][2]);
            const float e3 = EXP2F(st[mf][3]);
            l_part += (e0 + e1) + (e2 + e3);
            uint2 pw;
            pw.x = pk2h(e0, e1);
            pw.y = pk2h(e2, e3);
            const int key0 = mf * 16 + (cb << 2);
            const int p = (key0 >> 3) ^ (lq & 7);
            *(uint2*)&Ps[w][lq * 64 + p * 8 + (key0 & 7)] = pw;
        }
        {   // PV kb=1
            const int p1 = (4 + cb) ^ (lq & 7);
            f16x8 pf1 = *(const f16x8*)&Ps[w][lq * 64 + p1 * 8];
            __builtin_amdgcn_s_setprio(1);
#pragma unroll
            for (int df = 0; df < 4; ++df) {
                const int r = df * 16 + lq;
                const int p = (4 + cb) ^ (r & 7);
                f16x8 vf = *(const f16x8*)&Vs[BUF][r * 64 + p * 8];
                acc[df] = __builtin_amdgcn_mfma_f32_16x16x32_f16(vf, pf1, acc[df], 0, 0, 0);
            }
            __builtin_amdgcn_s_setprio(0);
        }
    };

    // one step = wait pair j -> barrier -> compute 2 tiles -> barrier -> issue j+2
    auto step = [&](const int PH, const bool ISSUE, const bool LAST) {
        if (LAST) asm volatile("s_waitcnt vmcnt(0)" ::: "memory");
        else      asm volatile("s_waitcnt vmcnt(4)" ::: "memory");
        __builtin_amdgcn_sched_barrier(0);
        __builtin_amdgcn_s_barrier();
        compute(PH ? 2 : 0);
        compute(PH ? 3 : 1);
        if (ISSUE) {
            __builtin_amdgcn_sched_barrier(0);
            asm volatile("s_waitcnt lgkmcnt(0)" ::: "memory");   // own reads drained (~free)
            __builtin_amdgcn_s_barrier();                         // all reads of pair j done
            __builtin_amdgcn_sched_barrier(0);
            if (PH) issue_pair(2, 3); else issue_pair(0, 1);      // pair j+2 -> freed bufs
        }
    };

    // 16 tile-pairs: j=0..13 issue, j=14,15 drain
#pragma unroll 1
    for (int i = 0; i < 7; ++i) {
        step(0, true, false);
        step(1, true, false);
    }
    step(0, false, false);  // j=14 (pair 15 still in flight)
    step(1, false, true);   // j=15 (final drain)

    // ---- epilogue: reduce l across the 4 cb groups; write ctx fp16 ----
    {
        float l_tot = l_part;
        l_tot += __shfl_xor(l_tot, 16);
        l_tot += __shfl_xor(l_tot, 32);
        const float inv = 1.0f / l_tot;
        const int s = q0 + lq;
#pragma unroll
        for (int df = 0; df < 4; ++df) {
            const int e0 = h * 64 + df * 16 + (cb << 2);
            ushort4 hv;
            hv.x = f2h(acc[df][0] * inv);
            hv.y = f2h(acc[df][1] * inv);
            hv.z = f2h(acc[df][2] * inv);
            hv.w = f2h(acc[df][3] * inv);
            *(ushort4*)&ch[(size_t)(b * SEQ + s) * DM + e0] = hv;
        }
    }
}

extern "C" void kernel_launch(void* const* d_in, const int* in_sizes, int n_in,
                              void* d_out, int out_size, void* d_ws, size_t ws_size,
                              hipStream_t stream)
{
    const float* x  = (const float*)d_in[0];
    const int* mask = (const int*)d_in[1];
    const float* wq = (const float*)d_in[2];
    const float* bq = (const float*)d_in[3];
    const float* wk = (const float*)d_in[4];
    const float* bk = (const float*)d_in[5];
    const float* wv = (const float*)d_in[6];
    const float* bv = (const float*)d_in[7];
    const float* wo = (const float*)d_in[8];
    const float* bo = (const float*)d_in[9];
    float* out = (float*)d_out;

    const size_t M1 = 1024 * 1024;      // 1M elements
    ushort* W = (ushort*)d_ws;          // fp16 arena (40 MB used)
    ushort* xH = W;                     // 4M  (doubles as ctx after attn)
    ushort* wH = W + 4 * M1;            // 4M: wq|wk|wv|wo
    ushort* QH = W + 8 * M1;
    ushort* KH = W + 12 * M1;
    ushort* VH = W + 16 * M1;

    cvt_all<<<2048, 256, 0, stream>>>(x, wq, wk, wv, wo, xH, wH);

    gemm5<384, 128, 4, 2, 0><<<256, 512, 0, stream>>>(
        wH, xH, bq, bk, bv, QH, KH, VH, nullptr, 8);

    // attention: 512 blocks (32 bh x 16 q-tiles, XCD-swizzled), 8 waves each
    attn_k<<<512, 512, 0, stream>>>(QH, KH, VH, mask, xH);

    gemm5<128, 128, 2, 2, 1><<<256, 256, 0, stream>>>(
        wH + 3 * M1, xH, bo, nullptr, nullptr,
        nullptr, nullptr, nullptr, out, 8);
}